// Round 7
// baseline (1473.263 us; speedup 1.0000x reference)
//
#include <hip/hip_runtime.h>
#include <hip/hip_fp16.h>

#define N_NODES 10000
#define N_EDGES 40000
#define N_GRAPH 64
#define KKREAL  262144          // 4096 * 64
#define KKTOT   262272          // + 128 (virtual k=4096 bias rank + zero pad)
#define CPS     257             // chunks per slice (uniform alloc; slices 0-6 use 256)
#define EPAD    40192           // 157 * 256 padded edge count
#define PSLICE  (EPAD * 64)     // floats per partial slice

typedef _Float16 half8_t  __attribute__((ext_vector_type(8)));
typedef float    floatx16 __attribute__((ext_vector_type(16)));

__device__ __forceinline__ void gload_lds16(const void* g, void* l) {
  __builtin_amdgcn_global_load_lds((const __attribute__((address_space(1))) void*)g,
                                   (__attribute__((address_space(3))) void*)l, 16, 0, 0);
}

// swizzle: 16B-slot permutation within each row's 256B chunk image (row bits 0-2)
__device__ __host__ __forceinline__ int swz(int row) {
  return ((row & 3) << 1) | ((row >> 2) & 1);
}

__device__ __forceinline__ half8_t splat8(_Float16 v) {
  half8_t r = {v, v, v, v, v, v, v, v};
  return r;
}

// ---------------- prep: BC[ks][c][row][128 halves], chunk-major, PRE-SWIZZLED
// so a linear global_load_lds DMA lands the bank-conflict-free LDS image.
// logical B'[o][kk_l] = w2_1[k][i*64+o] (kk_l = k*64+i), bias rank at k=4096.
// One thread per (ks, c, o) row writes 128 contiguous halves.
__global__ void prep_B(const float* __restrict__ w2, const float* __restrict__ b2,
                       _Float16* __restrict__ BC) {
  int tid = blockIdx.x * 256 + threadIdx.x;
  if (tid >= 8 * CPS * 64) return;
  int ks  = tid / (CPS * 64);
  int rem = tid - ks * (CPS * 64);
  int c = rem >> 6;
  int o = rem & 63;
  if (c == 256 && ks != 7) return;          // pad chunk, never read
  _Float16* dst = BC + (size_t)tid * 128;
  int swo = swz(o);
  int kkbase = ks * 32768 + c * 128;
  for (int sp = 0; sp < 16; ++sp) {         // physical 16B slot
    int kk0 = kkbase + ((sp ^ swo) * 8);    // logical joint-kk of this slot
    #pragma unroll
    for (int j3 = 0; j3 < 8; ++j3) {
      int kk_l = kk0 + j3;
      int k = kk_l >> 6, i = kk_l & 63;
      float v;
      if (k < 4096)       v = w2[k * 4096 + i * 64 + o];
      else if (k == 4096) v = b2[i * 64 + o];
      else                v = 0.f;
      dst[sp * 8 + j3] = (_Float16)v;
    }
  }
}

// ---------------- layer 0: per-edge MLP (in_dim=1) + scatter-sum + degree count
__global__ void layer0_edge(const float* __restrict__ node_ids,
                            const int* __restrict__ ei,
                            const float* __restrict__ ea,
                            const float* __restrict__ w1, const float* __restrict__ b1,
                            const float* __restrict__ w2, const float* __restrict__ b2,
                            float* __restrict__ agg0, float* __restrict__ cnt) {
  __shared__ float w1s[256], b1s[64], w2s[4096], b2s[64], zb[4][64];
  int t = threadIdx.x;
  for (int idx = t; idx < 4096; idx += 256) w2s[idx] = w2[idx];
  if (t < 256) w1s[t] = w1[t];
  if (t < 64) { b1s[t] = b1[t]; b2s[t] = b2[t]; }
  __syncthreads();
  int w = t >> 6, l = t & 63;
  int gw = blockIdx.x * 4 + w;
  int nw = gridDim.x * 4;
  for (int e = gw; e < N_EDGES; e += nw) {
    float a0 = ea[e * 4 + 0], a1 = ea[e * 4 + 1], a2 = ea[e * 4 + 2], a3 = ea[e * 4 + 3];
    float z = a0 * w1s[l] + a1 * w1s[64 + l] + a2 * w1s[128 + l] + a3 * w1s[192 + l] + b1s[l];
    zb[w][l] = fmaxf(z, 0.f);
    asm volatile("s_waitcnt lgkmcnt(0)" ::: "memory");
    __builtin_amdgcn_sched_barrier(0);
    float h = b2s[l];
    #pragma unroll
    for (int k = 0; k < 64; ++k) h += zb[w][k] * w2s[k * 64 + l];
    int src = ei[e], dst = ei[N_EDGES + e];
    float msg = node_ids[src] * h;
    atomicAdd(&agg0[dst * 64 + l], msg);
    if (l == 0) atomicAdd(&cnt[dst], 1.0f);
  }
}

// ---------------- node update 0: x1 = relu(agg0/cnt + node_ids*root0 + bias0); pool counts
__global__ void node0(const float* __restrict__ node_ids, const int* __restrict__ batch,
                      const float* __restrict__ agg0, const float* __restrict__ cnt,
                      const float* __restrict__ root0, const float* __restrict__ bias0,
                      float* __restrict__ x1, float* __restrict__ pcnt) {
  int gid = blockIdx.x * 256 + threadIdx.x;
  if (gid >= N_NODES * 64) return;
  int n = gid >> 6, o = gid & 63;
  float c = fmaxf(cnt[n], 1.f);
  float v = agg0[gid] / c + node_ids[n] * root0[o] + bias0[o];
  x1[gid] = fmaxf(v, 0.f);
  if (o == 0) atomicAdd(&pcnt[batch[n]], 1.0f);
}

// ---------------- layer 1 fused: msg[e,o] = sum_kk (z_e[k]*x_e[i]) * B'[kk,o]
// grid = 157 edge-blocks * 8 K-slices; block = 256 thr = 4 waves.
// Wave: 64 edges (2 tiles of 32) x ALL 64 o (n=2): each A-build feeds 2 MFMAs.
template <bool PART>
__launch_bounds__(256, 4)
__global__ void fused_edge_gemm(const int* __restrict__ ei,
                                const float* __restrict__ ea,
                                const float* __restrict__ x1,
                                const float* __restrict__ w1, const float* __restrict__ b1,
                                const _Float16* __restrict__ BC,
                                float* __restrict__ outbuf) {
  __shared__ __attribute__((aligned(16))) _Float16 Bl[2][64 * 128]; // swizzled image
  __shared__ __attribute__((aligned(16))) __half2 w1q[256][4];      // 4 w1 pairs per c
  __shared__ __half2 b1p[256];
  int t = threadIdx.x;
  int ks = blockIdx.x & 7;           // K-slice
  int eb = blockIdx.x >> 3;
  int e0 = eb * 256;
  int w = t >> 6, l = t & 63;
  int half_ = l >> 5;                // A/B fragment k-half
  int lane31 = l & 31;
  int swo = swz(lane31);             // same for lane31 and lane31+32 (bits 0-2 only)

  int kb = ks * 512;                 // real-k base of this slice
  {
    int j = t;
    #pragma unroll
    for (int d = 0; d < 4; ++d) {
      float2 v = *(const float2*)(w1 + d * 4096 + kb + 2 * j);
      w1q[j][d] = __floats2half2_rn(v.x, v.y);
    }
    float2 bv = *(const float2*)(b1 + kb + 2 * j);
    b1p[j] = __floats2half2_rn(bv.x, bv.y);
  }

  // per-lane A data: 2 edge-tiles of 32; lane holds x[row=lane31][q*16 + half_*8 + 0..7]
  half8_t xh8[2][4];
  __half2 ea01[2], ea23[2];          // packed edge attrs (a0,a1),(a2,a3)
  #pragma unroll
  for (int m = 0; m < 2; ++m) {
    int e = e0 + w * 64 + m * 32 + lane31;
    if (e < N_EDGES) {
      int src = ei[e];
      const float* xp = x1 + src * 64 + half_ * 8;
      #pragma unroll
      for (int q = 0; q < 4; ++q) {
        float4 f0 = *(const float4*)(xp + q * 16);
        float4 f1 = *(const float4*)(xp + q * 16 + 4);
        half8_t v;
        v[0] = (_Float16)f0.x; v[1] = (_Float16)f0.y;
        v[2] = (_Float16)f0.z; v[3] = (_Float16)f0.w;
        v[4] = (_Float16)f1.x; v[5] = (_Float16)f1.y;
        v[6] = (_Float16)f1.z; v[7] = (_Float16)f1.w;
        xh8[m][q] = v;
      }
      float4 av = *(const float4*)(ea + e * 4);
      ea01[m] = __floats2half2_rn(av.x, av.y);
      ea23[m] = __floats2half2_rn(av.z, av.w);
    } else {
      #pragma unroll
      for (int q = 0; q < 4; ++q) xh8[m][q] = splat8((_Float16)0.f);
      ea01[m] = __float2half2_rn(0.f);
      ea23[m] = __float2half2_rn(0.f);
    }
  }

  floatx16 acc[2][2];
  #pragma unroll
  for (int m = 0; m < 2; ++m)
    #pragma unroll
    for (int n = 0; n < 2; ++n)
      #pragma unroll
      for (int r = 0; r < 16; ++r) acc[m][n][r] = 0.f;

  int nchunk = (ks == 7) ? 257 : 256;

  // DMA source: ONE per-lane pointer into the chunk-major pre-swizzled image.
  // stage j covers rows w*16+j*4+(l>>4), byte col (l&15)*16  ==  gp + j*1024
  // (j*1024 folds into the instruction's imm offset). Advance 16 KB per chunk.
  const char* gp = (const char*)BC + (size_t)ks * (CPS * 16384) + w * 4096 + l * 16;
  char* dst0 = (char*)&Bl[0][0] + w * 4096 + l * 16;
  char* dst1 = (char*)&Bl[1][0] + w * 4096 + l * 16;

  auto stage = [&](char* dstb) {   // stage chunk at gp, then advance
    gload_lds16(gp,        dstb);
    gload_lds16(gp + 1024, dstb + 1024);
    gload_lds16(gp + 2048, dstb + 2048);
    gload_lds16(gp + 3072, dstb + 3072);
    gp += 16384;
  };

  stage(dst0);
  __syncthreads();

  const __half zero1 = __float2half(0.f);
  union H2F { __half2 h2; _Float16 f[2]; };

  int cur = 0;
  for (int c = 0; c < nchunk; ++c) {
    if (c + 1 < nchunk) stage(cur ? dst0 : dst1);   // DMA lands during compute

    // z for the chunk's two real k values -> splatted half8 multipliers
    half8_t zs8[2][2];
    if (c < 256) {
      __half2 w0 = w1q[c][0], w1v = w1q[c][1], w2v = w1q[c][2], w3v = w1q[c][3];
      __half2 bv = b1p[c];
      #pragma unroll
      for (int m = 0; m < 2; ++m) {
        __half2 h = __hfma2(__half2half2(__low2half(ea01[m])),  w0,  bv);
        h = __hfma2(__half2half2(__high2half(ea01[m])), w1v, h);
        h = __hfma2(__half2half2(__low2half(ea23[m])),  w2v, h);
        h = __hfma2(__half2half2(__high2half(ea23[m])), w3v, h);
        H2F u; u.h2 = __halves2half2(__hmax(__low2half(h),  zero1),
                                     __hmax(__high2half(h), zero1));
        zs8[m][0] = splat8(u.f[0]);
        zs8[m][1] = splat8(u.f[1]);
      }
    } else {  // bias chunk: k=4096 -> z=1 (picks up b2), k=4097 -> 0
      #pragma unroll
      for (int m = 0; m < 2; ++m) {
        zs8[m][0] = splat8((_Float16)1.f);
        zs8[m][1] = splat8((_Float16)0.f);
      }
    }

    const char* blc = (const char*)&Bl[cur][0] + lane31 * 256;
    #pragma unroll
    for (int t8 = 0; t8 < 8; ++t8) {            // kstep of 16 joint-kk
      int slot = (t8 * 2 + half_) ^ swo;
      const char* ba = blc + slot * 16;
      half8_t bf0 = *(const half8_t*)ba;             // o rows 0..31
      half8_t bf1 = *(const half8_t*)(ba + 8192);    // o rows 32..63 (same swizzle)
      #pragma unroll
      for (int m = 0; m < 2; ++m) {
        half8_t af = xh8[m][t8 & 3] * zs8[m][t8 >> 2];   // 4 v_pk_mul
        acc[m][0] = __builtin_amdgcn_mfma_f32_32x32x16_f16(af, bf0, acc[m][0], 0, 0, 0);
        acc[m][1] = __builtin_amdgcn_mfma_f32_32x32x16_f16(af, bf1, acc[m][1], 0, 0, 0);
      }
    }

    __syncthreads();   // all waves' DMAs drained (vmcnt) + reads of Bl[cur] done
    cur ^= 1;
  }

  // epilogue: 32x32 C/D layout: col=lane&31, row=(reg&3)+8*(reg>>2)+4*(lane>>5)
  if (PART) {
    float* pb = outbuf + ((size_t)ks * EPAD + e0 + w * 64) * 64 + lane31;
    #pragma unroll
    for (int m = 0; m < 2; ++m) {
      #pragma unroll
      for (int r = 0; r < 16; ++r) {
        int row = m * 32 + (r & 3) + 8 * (r >> 2) + 4 * half_;
        pb[(size_t)row * 64]      = acc[m][0][r];
        pb[(size_t)row * 64 + 32] = acc[m][1][r];
      }
    }
  } else {
    #pragma unroll
    for (int m = 0; m < 2; ++m) {
      #pragma unroll
      for (int r = 0; r < 16; ++r) {
        int e = e0 + w * 64 + m * 32 + (r & 3) + 8 * (r >> 2) + 4 * half_;
        if (e < N_EDGES) {
          int dst = ei[N_EDGES + e];
          atomicAdd(&outbuf[dst * 64 + lane31],      acc[m][0][r]);
          atomicAdd(&outbuf[dst * 64 + lane31 + 32], acc[m][1][r]);
        }
      }
    }
  }
}

// ---------------- reduce 8 partial slices -> scatter into agg1 (8x fewer atomics)
__global__ void reduce_partials(const float* __restrict__ P8, const int* __restrict__ ei,
                                float* __restrict__ agg1) {
  int gid = blockIdx.x * 256 + threadIdx.x;
  if (gid >= N_EDGES * 64) return;
  int e = gid >> 6;
  float s = 0.f;
  #pragma unroll
  for (int ks = 0; ks < 8; ++ks) s += P8[(size_t)ks * PSLICE + gid];
  int dst = ei[N_EDGES + e];
  atomicAdd(&agg1[dst * 64 + (gid & 63)], s);
}

// ---------------- node update 1 + global mean pool accumulate
__global__ void node1_pool(const int* __restrict__ batch, const float* __restrict__ x1,
                           const float* __restrict__ agg1, const float* __restrict__ cnt,
                           const float* __restrict__ root1, const float* __restrict__ bias1,
                           float* __restrict__ psum) {
  __shared__ float rt[4096];
  int t = threadIdx.x;
  for (int idx = t; idx < 4096; idx += 256) rt[idx] = root1[idx];
  __syncthreads();
  int w = t >> 6, l = t & 63;
  int n = blockIdx.x * 4 + w;
  if (n >= N_NODES) return;
  float c = fmaxf(cnt[n], 1.f);
  float acc = agg1[n * 64 + l] / c + bias1[l];
  const float* xp = x1 + n * 64;
  #pragma unroll
  for (int i4 = 0; i4 < 16; ++i4) {
    float4 xv = *(const float4*)(xp + i4 * 4);
    acc += xv.x * rt[(i4 * 4 + 0) * 64 + l] + xv.y * rt[(i4 * 4 + 1) * 64 + l]
         + xv.z * rt[(i4 * 4 + 2) * 64 + l] + xv.w * rt[(i4 * 4 + 3) * 64 + l];
  }
  acc = fmaxf(acc, 0.f);
  atomicAdd(&psum[batch[n] * 64 + l], acc);
}

// ---------------- classifier head: one wave per graph
__global__ void classifier(const float* __restrict__ psum, const float* __restrict__ pcnt,
                           const float* __restrict__ wc1, const float* __restrict__ bc1,
                           const float* __restrict__ wc2, const float* __restrict__ bc2,
                           float* __restrict__ out) {
  __shared__ float hb[64];
  int g = blockIdx.x, j = threadIdx.x;
  float c = fmaxf(pcnt[g], 1.f);
  float h = bc1[j];
  const float* pp = psum + g * 64;
  #pragma unroll
  for (int i4 = 0; i4 < 16; ++i4) {
    float4 pv = *(const float4*)(pp + i4 * 4);
    h += (pv.x / c) * wc1[(i4 * 4 + 0) * 64 + j] + (pv.y / c) * wc1[(i4 * 4 + 1) * 64 + j]
       + (pv.z / c) * wc1[(i4 * 4 + 2) * 64 + j] + (pv.w / c) * wc1[(i4 * 4 + 3) * 64 + j];
  }
  hb[j] = fmaxf(h, 0.f);
  __syncthreads();
  if (j < 4) {
    float o = bc2[j];
    #pragma unroll
    for (int k = 0; k < 64; ++k) o += hb[k] * wc2[k * 4 + j];
    out[g * 4 + j] = o;
  }
}

extern "C" void kernel_launch(void* const* d_in, const int* in_sizes, int n_in,
                              void* d_out, int out_size, void* d_ws, size_t ws_size,
                              hipStream_t stream) {
  const float* node_ids = (const float*)d_in[0];
  const int*   ei       = (const int*)d_in[1];
  const float* ea       = (const float*)d_in[2];
  const int*   batch    = (const int*)d_in[3];
  const float* w1_0 = (const float*)d_in[4];
  const float* b1_0 = (const float*)d_in[5];
  const float* w2_0 = (const float*)d_in[6];
  const float* b2_0 = (const float*)d_in[7];
  const float* root0 = (const float*)d_in[8];
  const float* bias0 = (const float*)d_in[9];
  const float* w1_1 = (const float*)d_in[10];
  const float* b1_1 = (const float*)d_in[11];
  const float* w2_1 = (const float*)d_in[12];
  const float* b2_1 = (const float*)d_in[13];
  const float* root1 = (const float*)d_in[14];
  const float* bias1 = (const float*)d_in[15];
  const float* wc1 = (const float*)d_in[16];
  const float* bc1 = (const float*)d_in[17];
  const float* wc2 = (const float*)d_in[18];
  const float* bc2 = (const float*)d_in[19];
  float* out = (float*)d_out;

  char* ws = (char*)d_ws;
  _Float16* BC = (_Float16*)ws;                        // 33,685,504 B (8*257*16384)
  float* x1   = (float*)(ws + 33685504);               //  2,560,000 B
  float* agg0 = (float*)(ws + 36245504);               //  2,560,000 B (zeroed)
  float* agg1 = (float*)(ws + 38805504);               //  2,560,000 B (zeroed)
  float* cnt  = (float*)(ws + 41365504);               //     40,000 B (zeroed)
  float* psum = (float*)(ws + 41405504);               //     16,384 B (zeroed)
  float* pcnt = (float*)(ws + 41421888);               //        256 B (zeroed)
  float* P8   = (float*)(ws + 41422144);               // 82,313,216 B (fully overwritten)
  const size_t NEED_PART = 41422144ull + (size_t)8 * PSLICE * 4;

  (void)hipMemsetAsync(agg0, 0, 2560000 + 2560000 + 40000 + 16384 + 256, stream);

  prep_B<<<(8 * CPS * 64 + 255) / 256, 256, 0, stream>>>(w2_1, b2_1, BC);
  layer0_edge<<<512, 256, 0, stream>>>(node_ids, ei, ea, w1_0, b1_0, w2_0, b2_0, agg0, cnt);
  node0<<<(N_NODES * 64 + 255) / 256, 256, 0, stream>>>(node_ids, batch, agg0, cnt, root0, bias0, x1, pcnt);

  if (ws_size >= NEED_PART) {
    fused_edge_gemm<true><<<157 * 8, 256, 0, stream>>>(ei, ea, x1, w1_1, b1_1, BC, P8);
    reduce_partials<<<(N_EDGES * 64) / 256, 256, 0, stream>>>(P8, ei, agg1);
  } else {
    fused_edge_gemm<false><<<157 * 8, 256, 0, stream>>>(ei, ea, x1, w1_1, b1_1, BC, agg1);
  }

  node1_pool<<<(N_NODES + 3) / 4, 256, 0, stream>>>(batch, x1, agg1, cnt, root1, bias1, psum);
  classifier<<<N_GRAPH, 64, 0, stream>>>(psum, pcnt, wc1, bc1, wc2, bc2, out);
}